// Round 15
// baseline (154.574 us; speedup 1.0000x reference)
//
#include <hip/hip_runtime.h>

#define NSEQ 4096
#define DIM  256
#define WIN  128
#define BATCH 4
#define REPEAT 8   // DIAGNOSTIC: repeat identical work to surface PMC rows + split fixed vs scaling cost

typedef __bf16 bf16x8 __attribute__((ext_vector_type(8)));
typedef float  f32x4  __attribute__((ext_vector_type(4)));
typedef int    v2i    __attribute__((ext_vector_type(2)));
typedef int    v4i    __attribute__((ext_vector_type(4)));

// subtiled layout (verified r2-r14)
__device__ __forceinline__ int sub_off(int j, int d) {
    return (((j >> 2) * 16 + (d >> 4)) << 6) + ((j & 3) << 4) + (d & 15);
}

__device__ __forceinline__ unsigned short f2bf(float f) {
    unsigned u = __builtin_bit_cast(unsigned, f);
    u += 0x7fffu + ((u >> 16) & 1u);   // RNE
    return (unsigned short)(u >> 16);
}

__device__ __forceinline__ unsigned pk2bf(float lo, float hi) {
    unsigned r;
    asm("v_cvt_pk_bf16_f32 %0, %1, %2" : "=v"(r) : "v"(lo), "v"(hi));
    return r;
}

__global__ __launch_bounds__(256, 3)
void sp_kernel(const float* __restrict__ val,
               const float* __restrict__ state,
               float* __restrict__ out) {
    __shared__ __align__(128) unsigned short vbuf[2][8192];  // 32 KB double buffer
    __shared__ __align__(128) unsigned short E_s[32 * 56];   // 3.5 KB
    __shared__ float ds_part[4][16];

    const int bx  = blockIdx.x;
    const int lbx = ((bx & 7) << 6) + (bx >> 3);
    const int b      = lbx >> 7;
    const int tile_i = lbx & 127;
    const int r0     = tile_i << 5;

    const int t   = threadIdx.x;
    const int w   = t >> 6;
    const int l   = t & 63;
    const int l15 = l & 15;
    const int l4  = l >> 4;
    const int mt  = w >> 1;
    const int jt  = w & 1;

    const int s_jl0 = (w << 2) + l4;
    const int s_jl1 = s_jl0 + 16;
    const int il = (mt << 4) + l15;
    const int jl = (jt << 4) + l15;
    const int tj0   = (tile_i >= 4) ? (tile_i - 4) : 0;
    const int ntile = tile_i - tj0 + 1;

    #pragma unroll 1
    for (int rep = 0; rep < REPEAT; ++rep) {
        // opaque per-pass pointers: block cross-pass CSE/hoisting (rule-17 sink)
        const float* valb = val + ((size_t)b * NSEQ) * DIM;
        const float* stb  = state + ((size_t)b * NSEQ);
        float* out_state  = out + ((size_t)b * NSEQ);
        float* out_val    = out + (size_t)BATCH * NSEQ + ((size_t)b * NSEQ) * DIM;
        asm volatile("" : "+v"(valb), "+v"(stb), "+v"(out_state), "+v"(out_val));

        __syncthreads();   // inter-pass safety

        // ---- prologue: stage tile_i into vbuf[0] ----
        {
            const float* src = valb + ((size_t)tile_i << 13);
            #pragma unroll
            for (int qq = 0; qq < 8; ++qq) {
                const int jl2 = (qq & 1) ? s_jl1 : s_jl0;
                const int d0 = (l15 << 2) + ((qq >> 1) << 6);
                float4 v = *reinterpret_cast<const float4*>(src + jl2 * DIM + d0);
                uint2 u;
                u.x = pk2bf(v.x, v.y);
                u.y = pk2bf(v.z, v.w);
                *reinterpret_cast<uint2*>(&vbuf[0][sub_off(jl2, d0)]) = u;
            }
        }
        __syncthreads();

        bf16x8 af[8];
        #pragma unroll
        for (int ks = 0; ks < 8; ++ks)
            af[ks] = *reinterpret_cast<const bf16x8*>(&vbuf[0][sub_off(il, (l4 << 3) + (ks << 5))]);

        float dsacc[4] = {0.f, 0.f, 0.f, 0.f};
        f32x4 accpv[2][4];
        #pragma unroll
        for (int m2 = 0; m2 < 2; ++m2)
            #pragma unroll
            for (int tt = 0; tt < 4; ++tt)
                accpv[m2][tt] = (f32x4){0.f, 0.f, 0.f, 0.f};

        int p = 0;
        for (int q = 0; q < ntile; ++q) {
            const int ti = tile_i - q;
            const bool havenext = (q + 1 < ntile);
            const unsigned short* bp = &vbuf[p][0];
            unsigned short* bn = &vbuf[1 - p][0];

            const int jg = (ti << 5) + jl;
            const float stv = stb[jg];

            bf16x8 sb[8];
            #pragma unroll
            for (int ks = 0; ks < 8; ++ks)
                sb[ks] = *reinterpret_cast<const bf16x8*>(&bp[sub_off(jl, (l4 << 3) + (ks << 5))]);
            f32x4 acc = (f32x4){0.f, 0.f, 0.f, 0.f};
            __builtin_amdgcn_s_setprio(1);
            #pragma unroll
            for (int ks = 0; ks < 8; ++ks)
                acc = __builtin_amdgcn_mfma_f32_16x16x32_bf16(af[ks], sb[ks], acc, 0, 0, 0);
            __builtin_amdgcn_s_setprio(0);

            const int ib = r0 + (mt << 4) + (l4 << 2);
            #pragma unroll
            for (int r = 0; r < 4; ++r) {
                float s = acc[r] * 0.0625f;
                float e = s * __builtin_amdgcn_rcpf(1.0f + fabsf(s));
                const int ig = ib + r;
                if (jg > ig || jg < ig - WIN) e = 0.0f;
                dsacc[r] += e * stv;
                E_s[((mt << 4) + (l4 << 2) + r) * 56 + (jt << 4) + l15] = f2bf(e);
            }

            if (havenext) {
                const float* src = valb + ((size_t)(ti - 1) << 13);
                #pragma unroll
                for (int qq = 0; qq < 8; ++qq) {
                    const int jl2 = (qq & 1) ? s_jl1 : s_jl0;
                    const int d0  = (l15 << 2) + ((qq >> 1) << 6);
                    float4 v = *reinterpret_cast<const float4*>(src + jl2 * DIM + d0);
                    uint2 u;
                    u.x = pk2bf(v.x, v.y);
                    u.y = pk2bf(v.z, v.w);
                    *reinterpret_cast<uint2*>(&bn[sub_off(jl2, d0)]) = u;
                }
            }
            __syncthreads();   // barrier 1

            bf16x8 ef0 = *reinterpret_cast<const bf16x8*>(&E_s[l15 * 56 + (l4 << 3)]);
            bf16x8 ef1 = *reinterpret_cast<const bf16x8*>(&E_s[(16 + l15) * 56 + (l4 << 3)]);
            const unsigned lds_base = (unsigned)(size_t)bp;
            v2i tr[8];
            #pragma unroll
            for (int tt = 0; tt < 4; ++tt) {
                const int nt = (w << 2) + tt;
                unsigned a0 = lds_base + (unsigned)((((l4 << 5) + nt) << 7) + (l15 << 3));
                asm volatile("ds_read_b64_tr_b16 %0, %1" : "=v"(tr[2 * tt]) : "v"(a0) : "memory");
                asm volatile("ds_read_b64_tr_b16 %0, %1 offset:2048" : "=v"(tr[2 * tt + 1]) : "v"(a0) : "memory");
            }
            asm volatile("s_waitcnt lgkmcnt(0)" ::: "memory");
            __builtin_amdgcn_sched_barrier(0);
            __builtin_amdgcn_s_setprio(1);
            #pragma unroll
            for (int tt = 0; tt < 4; ++tt) {
                v4i tmp;
                tmp.x = tr[2 * tt].x;     tmp.y = tr[2 * tt].y;
                tmp.z = tr[2 * tt + 1].x; tmp.w = tr[2 * tt + 1].y;
                bf16x8 bfr = __builtin_bit_cast(bf16x8, tmp);
                accpv[0][tt] = __builtin_amdgcn_mfma_f32_16x16x32_bf16(ef0, bfr, accpv[0][tt], 0, 0, 0);
                accpv[1][tt] = __builtin_amdgcn_mfma_f32_16x16x32_bf16(ef1, bfr, accpv[1][tt], 0, 0, 0);
            }
            __builtin_amdgcn_s_setprio(0);
            if (havenext) __syncthreads();   // barrier 2
            p ^= 1;
        }

        // ---- delta_state ----
        #pragma unroll
        for (int m = 1; m <= 8; m <<= 1) {
            #pragma unroll
            for (int r = 0; r < 4; ++r)
                dsacc[r] += __shfl_xor(dsacc[r], m, 64);
        }
        if (l15 == 0) {
            #pragma unroll
            for (int r = 0; r < 4; ++r)
                ds_part[w][(l4 << 2) + r] = dsacc[r];
        }
        __syncthreads();
        if (t < 32) {
            const int m2 = t >> 4;
            out_state[r0 + t] = ds_part[(m2 << 1)][t & 15] + ds_part[(m2 << 1) + 1][t & 15];
        }

        // ---- delta_val epilogue ----
        #pragma unroll
        for (int m2 = 0; m2 < 2; ++m2) {
            #pragma unroll
            for (int tt = 0; tt < 4; ++tt) {
                const int d = (w << 6) + (tt << 4) + l15;
                #pragma unroll
                for (int r = 0; r < 4; ++r) {
                    const int ig = r0 + (m2 << 4) + (l4 << 2) + r;
                    out_val[(size_t)ig * DIM + d] = accpv[m2][tt][r];
                }
            }
        }
    }
}

extern "C" void kernel_launch(void* const* d_in, const int* in_sizes, int n_in,
                              void* d_out, int out_size, void* d_ws, size_t ws_size,
                              hipStream_t stream) {
    const float* val   = (const float*)d_in[0];
    const float* state = (const float*)d_in[1];
    float* out = (float*)d_out;
    sp_kernel<<<dim3(BATCH * (NSEQ / 32)), dim3(256), 0, stream>>>(val, state, out);
}

// Round 16
// 27.720 us; speedup vs baseline: 5.5763x; 5.5763x over previous
//
#include <hip/hip_runtime.h>

#define NSEQ 4096
#define DIM  256
#define WIN  128
#define BATCH 4

typedef __bf16 bf16x8 __attribute__((ext_vector_type(8)));
typedef float  f32x4  __attribute__((ext_vector_type(4)));
typedef int    v2i    __attribute__((ext_vector_type(2)));
typedef int    v4i    __attribute__((ext_vector_type(4)));

// subtiled layout (verified r2-r15)
__device__ __forceinline__ int sub_off(int j, int d) {
    return (((j >> 2) * 16 + (d >> 4)) << 6) + ((j & 3) << 4) + (d & 15);
}

__device__ __forceinline__ unsigned short f2bf(float f) {
    unsigned u = __builtin_bit_cast(unsigned, f);
    u += 0x7fffu + ((u >> 16) & 1u);   // RNE
    return (unsigned short)(u >> 16);
}

__device__ __forceinline__ unsigned pk2bf(float lo, float hi) {
    unsigned r;
    asm("v_cvt_pk_bf16_f32 %0, %1, %2" : "=v"(r) : "v"(lo), "v"(hi));
    return r;
}

__global__ __launch_bounds__(256, 4)   // lean body fits 128-VGPR cap (r15: demand ~84) -> 4 blocks/CU, 16 waves
void sp_kernel(const float* __restrict__ val,
               const float* __restrict__ state,
               float* __restrict__ out) {
    __shared__ __align__(128) unsigned short vbuf[2][8192];  // 32 KB double buffer
    __shared__ __align__(128) unsigned short E_s[32 * 56];   // 3.5 KB
    __shared__ float ds_part[4][16];

    // XCD-aware bijective swizzle (512 = 8*64)
    const int bx  = blockIdx.x;
    const int lbx = ((bx & 7) << 6) + (bx >> 3);
    const int b      = lbx >> 7;
    const int tile_i = lbx & 127;
    const int r0     = tile_i << 5;

    const int t   = threadIdx.x;
    const int w   = t >> 6;
    const int l   = t & 63;
    const int l15 = l & 15;
    const int l4  = l >> 4;
    const int mt  = w >> 1;            // score row-tile (0..1)
    const int jt  = w & 1;             // score col-tile (0..1)

    const float* valb = val + ((size_t)b * NSEQ) * DIM;
    const float* stb  = state + ((size_t)b * NSEQ);
    float* out_state  = out + ((size_t)b * NSEQ);
    float* out_val    = out + (size_t)BATCH * NSEQ + ((size_t)b * NSEQ) * DIM;

    // staging row pattern
    const int s_jl0 = (w << 2) + l4;
    const int s_jl1 = s_jl0 + 16;

    // ---- prologue: stage tile_i into vbuf[0] ----
    {
        const float* src = valb + ((size_t)tile_i << 13);
        #pragma unroll
        for (int qq = 0; qq < 8; ++qq) {
            const int jl2 = (qq & 1) ? s_jl1 : s_jl0;
            const int d0 = (l15 << 2) + ((qq >> 1) << 6);
            float4 v = *reinterpret_cast<const float4*>(src + jl2 * DIM + d0);
            uint2 u;
            u.x = pk2bf(v.x, v.y);
            u.y = pk2bf(v.z, v.w);
            *reinterpret_cast<uint2*>(&vbuf[0][sub_off(jl2, d0)]) = u;
        }
    }
    __syncthreads();

    // ---- A-fragments (Vi rows), registers for whole loop ----
    const int il = (mt << 4) + l15;
    const int jl = (jt << 4) + l15;
    bf16x8 af[8];
    #pragma unroll
    for (int ks = 0; ks < 8; ++ks)
        af[ks] = *reinterpret_cast<const bf16x8*>(&vbuf[0][sub_off(il, (l4 << 3) + (ks << 5))]);

    const int tj0   = (tile_i >= 4) ? (tile_i - 4) : 0;
    const int ntile = tile_i - tj0 + 1;

    float dsacc[4] = {0.f, 0.f, 0.f, 0.f};
    f32x4 accpv[2][4];
    #pragma unroll
    for (int m2 = 0; m2 < 2; ++m2)
        #pragma unroll
        for (int tt = 0; tt < 4; ++tt)
            accpv[m2][tt] = (f32x4){0.f, 0.f, 0.f, 0.f};

    int p = 0;
    for (int q = 0; q < ntile; ++q) {
        const int ti = tile_i - q;
        const bool havenext = (q + 1 < ntile);
        const unsigned short* bp = &vbuf[p][0];
        unsigned short* bn = &vbuf[1 - p][0];

        const int jg = (ti << 5) + jl;
        const float stv = stb[jg];

        // ---- scores: sb read at use ----
        bf16x8 sb[8];
        #pragma unroll
        for (int ks = 0; ks < 8; ++ks)
            sb[ks] = *reinterpret_cast<const bf16x8*>(&bp[sub_off(jl, (l4 << 3) + (ks << 5))]);
        f32x4 acc = (f32x4){0.f, 0.f, 0.f, 0.f};
        __builtin_amdgcn_s_setprio(1);
        #pragma unroll
        for (int ks = 0; ks < 8; ++ks)
            acc = __builtin_amdgcn_mfma_f32_16x16x32_bf16(af[ks], sb[ks], acc, 0, 0, 0);
        __builtin_amdgcn_s_setprio(0);

        // ---- edges: scale, softsign (fast rcp), mask; dsacc; E write ----
        const int ib = r0 + (mt << 4) + (l4 << 2);
        #pragma unroll
        for (int r = 0; r < 4; ++r) {
            float s = acc[r] * 0.0625f;      // / sqrt(256)
            float e = s * __builtin_amdgcn_rcpf(1.0f + fabsf(s));
            const int ig = ib + r;
            if (jg > ig || jg < ig - WIN) e = 0.0f;
            dsacc[r] += e * stv;
            E_s[((mt << 4) + (l4 << 2) + r) * 56 + (jt << 4) + l15] = f2bf(e);
        }

        // ---- stage next tile: load+cvt+write inline (short register lifetime) ----
        if (havenext) {
            const float* src = valb + ((size_t)(ti - 1) << 13);
            #pragma unroll
            for (int qq = 0; qq < 8; ++qq) {
                const int jl2 = (qq & 1) ? s_jl1 : s_jl0;
                const int d0  = (l15 << 2) + ((qq >> 1) << 6);
                float4 v = *reinterpret_cast<const float4*>(src + jl2 * DIM + d0);
                uint2 u;
                u.x = pk2bf(v.x, v.y);
                u.y = pk2bf(v.z, v.w);
                *reinterpret_cast<uint2*>(&bn[sub_off(jl2, d0)]) = u;
            }
        }
        __syncthreads();   // barrier 1: E + staged tile visible

        // ---- PV: E frags, tr_reads in two groups of 4 (lower live-register peak) ----
        bf16x8 ef0 = *reinterpret_cast<const bf16x8*>(&E_s[l15 * 56 + (l4 << 3)]);
        bf16x8 ef1 = *reinterpret_cast<const bf16x8*>(&E_s[(16 + l15) * 56 + (l4 << 3)]);
        const unsigned lds_base = (unsigned)(size_t)bp;
        #pragma unroll
        for (int g = 0; g < 2; ++g) {
            v2i tr[4];
            #pragma unroll
            for (int h = 0; h < 2; ++h) {
                const int tt = (g << 1) + h;
                const int nt = (w << 2) + tt;
                unsigned a0 = lds_base + (unsigned)((((l4 << 5) + nt) << 7) + (l15 << 3));
                asm volatile("ds_read_b64_tr_b16 %0, %1" : "=v"(tr[2 * h]) : "v"(a0) : "memory");
                asm volatile("ds_read_b64_tr_b16 %0, %1 offset:2048" : "=v"(tr[2 * h + 1]) : "v"(a0) : "memory");
            }
            asm volatile("s_waitcnt lgkmcnt(0)" ::: "memory");
            __builtin_amdgcn_sched_barrier(0);
            __builtin_amdgcn_s_setprio(1);
            #pragma unroll
            for (int h = 0; h < 2; ++h) {
                const int tt = (g << 1) + h;
                v4i tmp;
                tmp.x = tr[2 * h].x;     tmp.y = tr[2 * h].y;
                tmp.z = tr[2 * h + 1].x; tmp.w = tr[2 * h + 1].y;
                bf16x8 bfr = __builtin_bit_cast(bf16x8, tmp);
                accpv[0][tt] = __builtin_amdgcn_mfma_f32_16x16x32_bf16(ef0, bfr, accpv[0][tt], 0, 0, 0);
                accpv[1][tt] = __builtin_amdgcn_mfma_f32_16x16x32_bf16(ef1, bfr, accpv[1][tt], 0, 0, 0);
            }
            __builtin_amdgcn_s_setprio(0);
        }
        if (havenext) __syncthreads();   // barrier 2: bp/E reads done before reuse
        p ^= 1;
    }

    // ---- delta_state: shuffle-reduce 16 j-lanes, combine jt-halves via LDS ----
    #pragma unroll
    for (int m = 1; m <= 8; m <<= 1) {
        #pragma unroll
        for (int r = 0; r < 4; ++r)
            dsacc[r] += __shfl_xor(dsacc[r], m, 64);
    }
    if (l15 == 0) {
        #pragma unroll
        for (int r = 0; r < 4; ++r)
            ds_part[w][(l4 << 2) + r] = dsacc[r];
    }
    __syncthreads();
    if (t < 32) {
        const int m2 = t >> 4;
        out_state[r0 + t] = ds_part[(m2 << 1)][t & 15] + ds_part[(m2 << 1) + 1][t & 15];
    }

    // ---- delta_val epilogue: C layout col=lane&15, row=(lane>>4)*4+r (verified) ----
    #pragma unroll
    for (int m2 = 0; m2 < 2; ++m2) {
        #pragma unroll
        for (int tt = 0; tt < 4; ++tt) {
            const int d = (w << 6) + (tt << 4) + l15;
            #pragma unroll
            for (int r = 0; r < 4; ++r) {
                const int ig = r0 + (m2 << 4) + (l4 << 2) + r;
                out_val[(size_t)ig * DIM + d] = accpv[m2][tt][r];
            }
        }
    }
}

extern "C" void kernel_launch(void* const* d_in, const int* in_sizes, int n_in,
                              void* d_out, int out_size, void* d_ws, size_t ws_size,
                              hipStream_t stream) {
    const float* val   = (const float*)d_in[0];
    const float* state = (const float*)d_in[1];
    float* out = (float*)d_out;
    sp_kernel<<<dim3(BATCH * (NSEQ / 32)), dim3(256), 0, stream>>>(val, state, out);
}

// Round 17
// 16.391 us; speedup vs baseline: 9.4303x; 1.6911x over previous
//
#include <hip/hip_runtime.h>

#define NSEQ 4096
#define DIM  256
#define WIN  128
#define BATCH 4

typedef __bf16 bf16x8 __attribute__((ext_vector_type(8)));
typedef float  f32x4  __attribute__((ext_vector_type(4)));
typedef int    v2i    __attribute__((ext_vector_type(2)));
typedef int    v4i    __attribute__((ext_vector_type(4)));

// subtiled layout (verified r2-r16)
__device__ __forceinline__ int sub_off(int j, int d) {
    return (((j >> 2) * 16 + (d >> 4)) << 6) + ((j & 3) << 4) + (d & 15);
}

__device__ __forceinline__ unsigned short f2bf(float f) {
    unsigned u = __builtin_bit_cast(unsigned, f);
    u += 0x7fffu + ((u >> 16) & 1u);   // RNE
    return (unsigned short)(u >> 16);
}

__device__ __forceinline__ unsigned pk2bf(float lo, float hi) {
    unsigned r;
    asm("v_cvt_pk_bf16_f32 %0, %1, %2" : "=v"(r) : "v"(lo), "v"(hi));
    return r;
}

__global__ __launch_bounds__(256, 3)   // best measured config (r10: 16.5us)
void sp_kernel(const float* __restrict__ val,
               const float* __restrict__ state,
               float* __restrict__ out) {
    __shared__ __align__(128) unsigned short vbuf[2][8192];  // 32 KB double buffer
    __shared__ __align__(128) unsigned short E_s[32 * 56];   // 3.5 KB
    __shared__ float ds_part[4][16];

    // XCD-aware bijective swizzle (512 = 8*64)
    const int bx  = blockIdx.x;
    const int lbx = ((bx & 7) << 6) + (bx >> 3);
    const int b      = lbx >> 7;
    const int tile_i = lbx & 127;
    const int r0     = tile_i << 5;

    const int t   = threadIdx.x;
    const int w   = t >> 6;
    const int l   = t & 63;
    const int l15 = l & 15;
    const int l4  = l >> 4;
    const int mt  = w >> 1;            // score row-tile (0..1)
    const int jt  = w & 1;             // score col-tile (0..1)

    const float* valb = val + ((size_t)b * NSEQ) * DIM;
    const float* stb  = state + ((size_t)b * NSEQ);
    float* out_state  = out + ((size_t)b * NSEQ);
    float* out_val    = out + (size_t)BATCH * NSEQ + ((size_t)b * NSEQ) * DIM;

    // staging row pattern (verified conflict-free)
    const int s_jl0 = (w << 2) + l4;
    const int s_jl1 = s_jl0 + 16;

    // ---- prologue: stage tile_i into vbuf[0] ----
    {
        const float* src = valb + ((size_t)tile_i << 13);
        #pragma unroll
        for (int qq = 0; qq < 8; ++qq) {
            const int jl2 = (qq & 1) ? s_jl1 : s_jl0;
            const int d0 = (l15 << 2) + ((qq >> 1) << 6);
            float4 v = *reinterpret_cast<const float4*>(src + jl2 * DIM + d0);
            uint2 u;
            u.x = pk2bf(v.x, v.y);
            u.y = pk2bf(v.z, v.w);
            *reinterpret_cast<uint2*>(&vbuf[0][sub_off(jl2, d0)]) = u;
        }
    }
    __syncthreads();

    // ---- A-fragments (Vi rows), registers for whole loop ----
    const int il = (mt << 4) + l15;
    const int jl = (jt << 4) + l15;
    bf16x8 af[8];
    #pragma unroll
    for (int ks = 0; ks < 8; ++ks)
        af[ks] = *reinterpret_cast<const bf16x8*>(&vbuf[0][sub_off(il, (l4 << 3) + (ks << 5))]);

    const int tj0   = (tile_i >= 4) ? (tile_i - 4) : 0;
    const int ntile = tile_i - tj0 + 1;

    float dsacc[4] = {0.f, 0.f, 0.f, 0.f};
    f32x4 accpv[2][4];
    #pragma unroll
    for (int m2 = 0; m2 < 2; ++m2)
        #pragma unroll
        for (int tt = 0; tt < 4; ++tt)
            accpv[m2][tt] = (f32x4){0.f, 0.f, 0.f, 0.f};

    int p = 0;
    for (int q = 0; q < ntile; ++q) {
        const int ti = tile_i - q;
        const bool havenext = (q + 1 < ntile);
        const unsigned short* bp = &vbuf[p][0];
        unsigned short* bn = &vbuf[1 - p][0];

        const int jg = (ti << 5) + jl;
        const float stv = stb[jg];

        // ---- scores: sb read at use ----
        bf16x8 sb[8];
        #pragma unroll
        for (int ks = 0; ks < 8; ++ks)
            sb[ks] = *reinterpret_cast<const bf16x8*>(&bp[sub_off(jl, (l4 << 3) + (ks << 5))]);
        f32x4 acc = (f32x4){0.f, 0.f, 0.f, 0.f};
        #pragma unroll
        for (int ks = 0; ks < 8; ++ks)
            acc = __builtin_amdgcn_mfma_f32_16x16x32_bf16(af[ks], sb[ks], acc, 0, 0, 0);

        // ---- edges: scale, softsign (fast rcp), mask; dsacc; E write ----
        const int ib = r0 + (mt << 4) + (l4 << 2);
        #pragma unroll
        for (int r = 0; r < 4; ++r) {
            float s = acc[r] * 0.0625f;      // / sqrt(256)
            float e = s * __builtin_amdgcn_rcpf(1.0f + fabsf(s));
            const int ig = ib + r;
            if (jg > ig || jg < ig - WIN) e = 0.0f;
            dsacc[r] += e * stv;
            E_s[((mt << 4) + (l4 << 2) + r) * 56 + (jt << 4) + l15] = f2bf(e);
        }

        // ---- stage next tile: load+cvt+write inline ----
        if (havenext) {
            const float* src = valb + ((size_t)(ti - 1) << 13);
            #pragma unroll
            for (int qq = 0; qq < 8; ++qq) {
                const int jl2 = (qq & 1) ? s_jl1 : s_jl0;
                const int d0  = (l15 << 2) + ((qq >> 1) << 6);
                float4 v = *reinterpret_cast<const float4*>(src + jl2 * DIM + d0);
                uint2 u;
                u.x = pk2bf(v.x, v.y);
                u.y = pk2bf(v.z, v.w);
                *reinterpret_cast<uint2*>(&bn[sub_off(jl2, d0)]) = u;
            }
        }
        __syncthreads();   // barrier 1: E + staged tile visible

        // ---- PV: E frags, batched tr_reads (no "memory" clobber: barriers order LDS) ----
        bf16x8 ef0 = *reinterpret_cast<const bf16x8*>(&E_s[l15 * 56 + (l4 << 3)]);
        bf16x8 ef1 = *reinterpret_cast<const bf16x8*>(&E_s[(16 + l15) * 56 + (l4 << 3)]);
        const unsigned lds_base = (unsigned)(size_t)bp;
        v2i tr[8];
        #pragma unroll
        for (int tt = 0; tt < 4; ++tt) {
            const int nt = (w << 2) + tt;
            unsigned a0 = lds_base + (unsigned)((((l4 << 5) + nt) << 7) + (l15 << 3));
            asm volatile("ds_read_b64_tr_b16 %0, %1" : "=v"(tr[2 * tt]) : "v"(a0));
            asm volatile("ds_read_b64_tr_b16 %0, %1 offset:2048" : "=v"(tr[2 * tt + 1]) : "v"(a0));
        }
        asm volatile("s_waitcnt lgkmcnt(0)" ::: "memory");
        __builtin_amdgcn_sched_barrier(0);   // rule-18 fence: no MFMA hoist above the wait
        #pragma unroll
        for (int tt = 0; tt < 4; ++tt) {
            v4i tmp;
            tmp.x = tr[2 * tt].x;     tmp.y = tr[2 * tt].y;
            tmp.z = tr[2 * tt + 1].x; tmp.w = tr[2 * tt + 1].y;
            bf16x8 bfr = __builtin_bit_cast(bf16x8, tmp);
            accpv[0][tt] = __builtin_amdgcn_mfma_f32_16x16x32_bf16(ef0, bfr, accpv[0][tt], 0, 0, 0);
            accpv[1][tt] = __builtin_amdgcn_mfma_f32_16x16x32_bf16(ef1, bfr, accpv[1][tt], 0, 0, 0);
        }
        if (havenext) __syncthreads();   // barrier 2: bp/E reads done before reuse
        p ^= 1;
    }

    // ---- delta_state: shuffle-reduce 16 j-lanes, combine jt-halves via LDS ----
    #pragma unroll
    for (int m = 1; m <= 8; m <<= 1) {
        #pragma unroll
        for (int r = 0; r < 4; ++r)
            dsacc[r] += __shfl_xor(dsacc[r], m, 64);
    }
    if (l15 == 0) {
        #pragma unroll
        for (int r = 0; r < 4; ++r)
            ds_part[w][(l4 << 2) + r] = dsacc[r];
    }
    __syncthreads();
    if (t < 32) {
        const int m2 = t >> 4;
        out_state[r0 + t] = ds_part[(m2 << 1)][t & 15] + ds_part[(m2 << 1) + 1][t & 15];
    }

    // ---- delta_val epilogue: C layout col=lane&15, row=(lane>>4)*4+r (verified) ----
    #pragma unroll
    for (int m2 = 0; m2 < 2; ++m2) {
        #pragma unroll
        for (int tt = 0; tt < 4; ++tt) {
            const int d = (w << 6) + (tt << 4) + l15;
            #pragma unroll
            for (int r = 0; r < 4; ++r) {
                const int ig = r0 + (m2 << 4) + (l4 << 2) + r;
                out_val[(size_t)ig * DIM + d] = accpv[m2][tt][r];
            }
        }
    }
}

extern "C" void kernel_launch(void* const* d_in, const int* in_sizes, int n_in,
                              void* d_out, int out_size, void* d_ws, size_t ws_size,
                              hipStream_t stream) {
    const float* val   = (const float*)d_in[0];
    const float* state = (const float*)d_in[1];
    float* out = (float*)d_out;
    sp_kernel<<<dim3(BATCH * (NSEQ / 32)), dim3(256), 0, stream>>>(val, state, out);
}